// Round 10
// baseline (154.169 us; speedup 1.0000x reference)
//
#include <hip/hip_runtime.h>
#include <math.h>

#define BB 2
#define NN 512
#define NIN 64
#define NF 192
#define HH 128
#define NOUT 8

// Diagnostic round: idempotent repeat loops to surface per-kernel counters.
#define K1_REP 20
#define K2_REP 10

typedef short short8 __attribute__((ext_vector_type(8)));
typedef float f32x4 __attribute__((ext_vector_type(4)));

__device__ __forceinline__ float celu1(float x) {
    return x > 0.0f ? x : expm1f(x);
}

__device__ __forceinline__ ushort f2b(float f) {
    union { float f; uint u; } v; v.f = f;
    uint r = v.u + 0x7fffu + ((v.u >> 16) & 1u);   // RNE
    return (ushort)(r >> 16);
}
__device__ __forceinline__ uint pack2(float a, float b) {
    return (uint)f2b(a) | ((uint)f2b(b) << 16);
}
// load 8 consecutive f32, convert to a bf16 MFMA fragment in-register
__device__ __forceinline__ short8 cvt8(const float* __restrict__ p) {
    float4 a = *(const float4*)p;
    float4 b = *(const float4*)(p + 4);
    union { uint4 u; short8 s; } c;
    c.u.x = pack2(a.x, a.y); c.u.y = pack2(a.z, a.w);
    c.u.z = pack2(b.x, b.y); c.u.w = pack2(b.z, b.w);
    return c.s;
}

// t_s XOR swizzle (validated R6)
__device__ __forceinline__ ushort* tsw(ushort* t_s, int m, int col) {
    int key = (m ^ (m >> 3)) & 7;
    int byte = m * 256 + ((col * 2) ^ (key << 4));
    return (ushort*)((char*)t_s + byte);
}

// ---------------------------------------------------------------------------
// K1 (R4/R6-validated body, repeated K1_REP times, idempotent)
// ---------------------------------------------------------------------------
__global__ __launch_bounds__(256) void k1_kernel(
    const float* __restrict__ x_l, const float* __restrict__ x_r,
    const float* __restrict__ Wl, const float* __restrict__ bl,
    const float* __restrict__ Wr, const float* __restrict__ br,
    const float* __restrict__ Wb,
    ushort* __restrict__ hl_bf, ushort* __restrict__ hr_bf,
    ushort* __restrict__ Wt)
{
    __shared__ float lds[128 * 65];   // used only by transpose blocks
    int blk = blockIdx.x;
    int tid = threadIdx.x;

    for (int rep = 0; rep < K1_REP; ++rep) {
        if (blk < 256) {
            int mb = blk & 63;
            int lr = (blk >> 6) & 1;
            int hh = blk >> 7;
            int m0 = mb * 16;
            int b  = m0 >> 9;
            int i_base = m0 & (NN - 1);

            int wave = tid >> 6;
            int lane = tid & 63;
            int lrow = lane & 15;
            int lgrp = lane >> 4;
            int h0 = hh * 64 + wave * 16;
            int i = i_base + lrow;

            const float* Wm   = lr ? Wr : Wl;
            const float* bias = lr ? br : bl;
            const float* xa   = lr ? x_r : x_l;
            ushort* dst       = lr ? hr_bf : hl_bf;

            short8 bf[6];
            #pragma unroll
            for (int kk = 0; kk < 6; ++kk) {
                int part = kk >> 1;
                int c0 = (kk & 1) * 32 + lgrp * 8;
                int s; const float* src;
                if (part == 0)      { s = 0;            src = x_l; }
                else if (part == 1) { s = lr ? +1 : -1; src = xa; }
                else                { s = lr ? -1 : +1; src = xa; }
                int row = i + s;
                short8 v = (short8)0;
                if ((unsigned)row < (unsigned)NN)
                    v = cvt8(&src[(b * NN + row) * NIN + c0]);
                bf[kk] = v;
            }

            f32x4 acc = (f32x4)(0.0f);
            #pragma unroll
            for (int kk = 0; kk < 6; ++kk) {
                short8 afrag = cvt8(&Wm[(h0 + lrow) * NF + kk * 32 + lgrp * 8]);
                acc = __builtin_amdgcn_mfma_f32_16x16x32_bf16(afrag, bf[kk], acc, 0, 0, 0);
            }

            int h_base = h0 + lgrp * 4;
            float4 bv = *(const float4*)&bias[h_base];
            int m = m0 + lrow;
            uint2 v;
            v.x = pack2(celu1(acc[0] + bv.x), celu1(acc[1] + bv.y));
            v.y = pack2(celu1(acc[2] + bv.z), celu1(acc[3] + bv.w));
            *(uint2*)&dst[m * HH + h_base] = v;
        } else {
            int o = blk - 256;
            for (int h0 = 0; h0 < HH; h0 += 64) {
                for (int idx = tid; idx < 64 * 128; idx += 256) {
                    int hh = idx >> 7;           // 0..63
                    int g  = idx & 127;
                    lds[g * 65 + hh] = Wb[(o * HH + h0 + hh) * HH + g];
                }
                __syncthreads();
                for (int idx = tid; idx < 128 * 64; idx += 256) {
                    int g  = idx >> 6;           // 0..127
                    int hh = idx & 63;
                    Wt[(o * HH + g) * HH + h0 + hh] = f2b(lds[g * 65 + hh]);
                }
                __syncthreads();
            }
        }
        __syncthreads();
    }
}

// ---------------------------------------------------------------------------
// K2 (R6-validated body, repeated K2_REP times, idempotent)
// grid dim3(4, 32, 2), 512 threads (8 waves).
// ---------------------------------------------------------------------------
__global__ __launch_bounds__(512) void k2_kernel(
    const ushort* __restrict__ hl_bf, const ushort* __restrict__ hr_bf,
    const ushort* __restrict__ Wt, const float* __restrict__ bias,
    float* __restrict__ out)
{
    __shared__ ushort t_s[128 * 128];   // 32 KiB

    int j0 = blockIdx.x * 128;
    int i0 = blockIdx.y * 16;
    int b  = blockIdx.z;
    int tid  = threadIdx.x;
    int wave = tid >> 6;        // 0..7
    int lane = tid & 63;
    int lrow = lane & 15;
    int lgrp = lane >> 4;

    for (int rep = 0; rep < K2_REP; ++rep) {
        // ---- prefetch phase-2 B fragments (hr), one j-subtile per wave ----
        int jw = j0 + wave * 16;
        const ushort* hb = hr_bf + (size_t)b * NN * HH;
        short8 bfr[4];
        #pragma unroll
        for (int kk = 0; kk < 4; ++kk)
            bfr[kk] = *(const short8*)&hb[(jw + lrow) * HH + kk * 32 + lgrp * 8];

        // ---- phase 1: build t tile in swizzled LDS (wave w -> o = w) ----
        short8 hfrag[4];
        #pragma unroll
        for (int kk = 0; kk < 4; ++kk)
            hfrag[kk] = *(const short8*)&hl_bf[(b * NN + i0 + lrow) * HH + kk * 32 + lgrp * 8];

        int o_p1 = wave;
        #pragma unroll
        for (int gt = 0; gt < 8; ++gt) {
            int g_base = gt * 16;
            f32x4 acc = (f32x4)(0.0f);
            #pragma unroll
            for (int kk = 0; kk < 4; ++kk) {
                short8 afrag = *(const short8*)&Wt[(o_p1 * HH + g_base + lrow) * HH + kk * 32 + lgrp * 8];
                acc = __builtin_amdgcn_mfma_f32_16x16x32_bf16(afrag, hfrag[kk], acc, 0, 0, 0);
            }
            int m  = lrow * 8 + o_p1;
            int gg = g_base + lgrp * 4;
            uint2 v;
            v.x = pack2(acc[0], acc[1]);
            v.y = pack2(acc[2], acc[3]);
            *(uint2*)tsw(t_s, m, gg) = v;
        }
        __syncthreads();

        // ---- phase 2: A from LDS (swizzled), B already in registers ----
        f32x4 acc2[8];
        #pragma unroll
        for (int ms = 0; ms < 8; ++ms) acc2[ms] = (f32x4)(0.0f);

        #pragma unroll
        for (int kk = 0; kk < 4; ++kk) {
            int koff = kk * 32 + lgrp * 8;
            #pragma unroll
            for (int ms = 0; ms < 8; ++ms) {
                short8 afr = *(const short8*)tsw(t_s, ms * 16 + lrow, koff);
                acc2[ms] = __builtin_amdgcn_mfma_f32_16x16x32_bf16(afr, bfr[kk], acc2[ms], 0, 0, 0);
            }
        }

        // ---- epilogue ----
        float4 b0 = *(const float4*)&bias[0];
        float4 b1 = *(const float4*)&bias[4];
        int j = jw + lrow;

        #pragma unroll
        for (int ms = 0; ms < 8; ++ms) {
            int m_base = ms * 16 + lgrp * 4;       // multiple of 4
            int i  = i0 + (m_base >> 3);
            int o0 = m_base & 7;                   // 0 or 4
            float4 bv = o0 ? b1 : b0;
            float4 v;
            v.x = acc2[ms][0] + bv.x;
            v.y = acc2[ms][1] + bv.y;
            v.z = acc2[ms][2] + bv.z;
            v.w = acc2[ms][3] + bv.w;
            float* dst = out + ((size_t)((b * NN + i) * NN + j)) * NOUT + o0;
            *(float4*)dst = v;
        }
        __syncthreads();   // protect t_s WAR across repeats
    }
}

// ---------------------------------------------------------------------------
extern "C" void kernel_launch(void* const* d_in, const int* in_sizes, int n_in,
                              void* d_out, int out_size, void* d_ws, size_t ws_size,
                              hipStream_t stream) {
    const float* x_l  = (const float*)d_in[0];
    const float* x_r  = (const float*)d_in[1];
    const float* Wl   = (const float*)d_in[2];
    const float* bl   = (const float*)d_in[3];
    const float* Wr   = (const float*)d_in[4];
    const float* br   = (const float*)d_in[5];
    const float* Wb   = (const float*)d_in[6];
    const float* bb   = (const float*)d_in[7];
    float* out = (float*)d_out;

    ushort* hl_bf = (ushort*)d_ws;                   // B*N*H = 131072
    ushort* hr_bf = hl_bf + BB * NN * HH;            // 131072
    ushort* Wt    = hr_bf + BB * NN * HH;            // 8*128*128 = 131072

    k1_kernel<<<264, 256, 0, stream>>>(x_l, x_r, Wl, bl, Wr, br, Wb,
                                       hl_bf, hr_bf, Wt);
    k2_kernel<<<dim3(NN / 128, NN / 16, BB), 512, 0, stream>>>(
        hl_bf, hr_bf, Wt, bb, out);
}

// Round 11
// 26.833 us; speedup vs baseline: 5.7455x; 5.7455x over previous
//
#include <hip/hip_runtime.h>
#include <math.h>

#define BB 2
#define NN 512
#define NIN 64
#define NF 192
#define HH 128
#define NOUT 8

typedef short short8 __attribute__((ext_vector_type(8)));
typedef float f32x4 __attribute__((ext_vector_type(4)));

__device__ __forceinline__ float celu1(float x) {
    return x > 0.0f ? x : expm1f(x);
}

__device__ __forceinline__ ushort f2b(float f) {
    union { float f; uint u; } v; v.f = f;
    uint r = v.u + 0x7fffu + ((v.u >> 16) & 1u);   // RNE
    return (ushort)(r >> 16);
}
__device__ __forceinline__ uint pack2(float a, float b) {
    return (uint)f2b(a) | ((uint)f2b(b) << 16);
}
// pack two loaded float4s into a bf16 MFMA fragment
__device__ __forceinline__ short8 pack8(float4 a, float4 b) {
    union { uint4 u; short8 s; } c;
    c.u.x = pack2(a.x, a.y); c.u.y = pack2(a.z, a.w);
    c.u.z = pack2(b.x, b.y); c.u.w = pack2(b.z, b.w);
    return c.s;
}

// t_s XOR swizzle (validated R6)
__device__ __forceinline__ ushort* tsw(ushort* t_s, int m, int col) {
    int key = (m ^ (m >> 3)) & 7;
    int byte = m * 256 + ((col * 2) ^ (key << 4));
    return (ushort*)((char*)t_s + byte);
}

// ---------------------------------------------------------------------------
// K1 v2: latency-optimized fc + transpose.  Grid 272 x 512 threads (8 waves).
//
// Blocks [0,256): fc.  Job = one 16m x 16h output tile, K=192.
//   jid = bid*4 + (wave>>1);  jid = mb | lr<<6 | ht<<7  (ht: 16-h tile).
//   K-SPLIT: wave pair (2p, 2p+1) splits K: khalf = wave&1 -> kk in
//   [khalf*3, khalf*3+3).  2048 fc waves total = 2/SIMD (was 1/SIMD).
//   All 12 raw float4 loads issued before any cvt/MFMA (one waitcnt batch).
//   Partials combined via LDS f32x4; even wave adds bias, celu, packs, stores.
// Blocks [256,272): Wb transpose, 2 blocks per o: h-half = bid&1.
// ---------------------------------------------------------------------------
__global__ __launch_bounds__(512) void k1_kernel(
    const float* __restrict__ x_l, const float* __restrict__ x_r,
    const float* __restrict__ Wl, const float* __restrict__ bl,
    const float* __restrict__ Wr, const float* __restrict__ br,
    const float* __restrict__ Wb,
    ushort* __restrict__ hl_bf, ushort* __restrict__ hr_bf,
    ushort* __restrict__ Wt)
{
    __shared__ float lds_f[128 * 65];   // 33.3 KB; fc path uses first 8 KB

    int bid = blockIdx.x;
    int tid = threadIdx.x;
    int wave = tid >> 6;
    int lane = tid & 63;
    int lrow = lane & 15;
    int lgrp = lane >> 4;

    if (bid < 256) {
        int p     = wave >> 1;
        int khalf = wave & 1;
        int jid = bid * 4 + p;
        int mb = jid & 63;
        int lr = (jid >> 6) & 1;
        int ht = jid >> 7;                 // 0..7
        int m0 = mb * 16;
        int b  = m0 >> 9;
        int i_base = m0 & (NN - 1);
        int h0 = ht * 16;
        int i  = i_base + lrow;

        const float* Wm = lr ? Wr : Wl;
        const float* xa = lr ? x_r : x_l;

        // ---- issue ALL raw loads first (single waitcnt batch) ----
        float4 braw[3][2], araw[3][2];
        #pragma unroll
        for (int q = 0; q < 3; ++q) {
            int kk = khalf * 3 + q;
            int part = kk >> 1;
            int c0 = (kk & 1) * 32 + lgrp * 8;
            int s; const float* src;
            if (part == 0)      { s = 0;            src = x_l; }
            else if (part == 1) { s = lr ? +1 : -1; src = xa; }
            else                { s = lr ? -1 : +1; src = xa; }
            int row = i + s;
            if ((unsigned)row < (unsigned)NN) {
                const float* pp = &src[(b * NN + row) * NIN + c0];
                braw[q][0] = *(const float4*)pp;
                braw[q][1] = *(const float4*)(pp + 4);
            } else {
                braw[q][0] = float4{0.f, 0.f, 0.f, 0.f};
                braw[q][1] = float4{0.f, 0.f, 0.f, 0.f};
            }
            const float* wp = &Wm[(h0 + lrow) * NF + kk * 32 + lgrp * 8];
            araw[q][0] = *(const float4*)wp;
            araw[q][1] = *(const float4*)(wp + 4);
        }

        // ---- convert + 3 MFMAs ----
        f32x4 acc = (f32x4)(0.0f);
        #pragma unroll
        for (int q = 0; q < 3; ++q) {
            short8 bfrag = pack8(braw[q][0], braw[q][1]);
            short8 afrag = pack8(araw[q][0], araw[q][1]);
            acc = __builtin_amdgcn_mfma_f32_16x16x32_bf16(afrag, bfrag, acc, 0, 0, 0);
        }

        // ---- combine K-halves via LDS ----
        f32x4* part_s = (f32x4*)lds_f;      // [8][64]
        part_s[wave * 64 + lane] = acc;
        __syncthreads();

        if (khalf == 0) {
            f32x4 oth = part_s[(wave + 1) * 64 + lane];
            acc[0] += oth[0]; acc[1] += oth[1];
            acc[2] += oth[2]; acc[3] += oth[3];

            const float* bias = lr ? br : bl;
            ushort* dst       = lr ? hr_bf : hl_bf;
            int h_base = h0 + lgrp * 4;
            float4 bv = *(const float4*)&bias[h_base];
            int m = m0 + lrow;
            uint2 v;
            v.x = pack2(celu1(acc[0] + bv.x), celu1(acc[1] + bv.y));
            v.y = pack2(celu1(acc[2] + bv.z), celu1(acc[3] + bv.w));
            *(uint2*)&dst[m * HH + h_base] = v;
        }
    } else {
        // ---- Wb transpose: 16 blocks, o = t>>1, h-half = t&1 ----
        int t  = bid - 256;
        int o  = t >> 1;
        int h0 = (t & 1) * 64;
        for (int idx = tid; idx < 64 * 128; idx += 512) {
            int hh = idx >> 7;              // 0..63
            int g  = idx & 127;
            lds_f[g * 65 + hh] = Wb[(o * HH + h0 + hh) * HH + g];
        }
        __syncthreads();
        for (int idx = tid; idx < 128 * 64; idx += 512) {
            int g  = idx >> 6;              // 0..127
            int hh = idx & 63;
            Wt[(o * HH + g) * HH + h0 + hh] = f2b(lds_f[g * 65 + hh]);
        }
    }
}

// ---------------------------------------------------------------------------
// K2 (validated R6 body, unchanged — measured ~1.6 us/rep in R10).
// grid dim3(4, 32, 2), 512 threads (8 waves).
// ---------------------------------------------------------------------------
__global__ __launch_bounds__(512) void k2_kernel(
    const ushort* __restrict__ hl_bf, const ushort* __restrict__ hr_bf,
    const ushort* __restrict__ Wt, const float* __restrict__ bias,
    float* __restrict__ out)
{
    __shared__ ushort t_s[128 * 128];   // 32 KiB

    int j0 = blockIdx.x * 128;
    int i0 = blockIdx.y * 16;
    int b  = blockIdx.z;
    int tid  = threadIdx.x;
    int wave = tid >> 6;        // 0..7
    int lane = tid & 63;
    int lrow = lane & 15;
    int lgrp = lane >> 4;

    // ---- prefetch phase-2 B fragments (hr), one j-subtile per wave ----
    int jw = j0 + wave * 16;
    const ushort* hb = hr_bf + (size_t)b * NN * HH;
    short8 bfr[4];
    #pragma unroll
    for (int kk = 0; kk < 4; ++kk)
        bfr[kk] = *(const short8*)&hb[(jw + lrow) * HH + kk * 32 + lgrp * 8];

    // ---- phase 1: build t tile in swizzled LDS (wave w -> o = w) ----
    short8 hfrag[4];
    #pragma unroll
    for (int kk = 0; kk < 4; ++kk)
        hfrag[kk] = *(const short8*)&hl_bf[(b * NN + i0 + lrow) * HH + kk * 32 + lgrp * 8];

    int o_p1 = wave;
    #pragma unroll
    for (int gt = 0; gt < 8; ++gt) {
        int g_base = gt * 16;
        f32x4 acc = (f32x4)(0.0f);
        #pragma unroll
        for (int kk = 0; kk < 4; ++kk) {
            short8 afrag = *(const short8*)&Wt[(o_p1 * HH + g_base + lrow) * HH + kk * 32 + lgrp * 8];
            acc = __builtin_amdgcn_mfma_f32_16x16x32_bf16(afrag, hfrag[kk], acc, 0, 0, 0);
        }
        int m  = lrow * 8 + o_p1;
        int gg = g_base + lgrp * 4;
        uint2 v;
        v.x = pack2(acc[0], acc[1]);
        v.y = pack2(acc[2], acc[3]);
        *(uint2*)tsw(t_s, m, gg) = v;
    }
    __syncthreads();

    // ---- phase 2: A from LDS (swizzled), B already in registers ----
    f32x4 acc2[8];
    #pragma unroll
    for (int ms = 0; ms < 8; ++ms) acc2[ms] = (f32x4)(0.0f);

    #pragma unroll
    for (int kk = 0; kk < 4; ++kk) {
        int koff = kk * 32 + lgrp * 8;
        #pragma unroll
        for (int ms = 0; ms < 8; ++ms) {
            short8 afr = *(const short8*)tsw(t_s, ms * 16 + lrow, koff);
            acc2[ms] = __builtin_amdgcn_mfma_f32_16x16x32_bf16(afr, bfr[kk], acc2[ms], 0, 0, 0);
        }
    }

    // ---- epilogue: 4 consecutive D rows -> same i, o0..o0+3; float4 store ----
    float4 b0 = *(const float4*)&bias[0];
    float4 b1 = *(const float4*)&bias[4];
    int j = jw + lrow;

    #pragma unroll
    for (int ms = 0; ms < 8; ++ms) {
        int m_base = ms * 16 + lgrp * 4;       // multiple of 4
        int i  = i0 + (m_base >> 3);
        int o0 = m_base & 7;                   // 0 or 4
        float4 bv = o0 ? b1 : b0;
        float4 v;
        v.x = acc2[ms][0] + bv.x;
        v.y = acc2[ms][1] + bv.y;
        v.z = acc2[ms][2] + bv.z;
        v.w = acc2[ms][3] + bv.w;
        float* dst = out + ((size_t)((b * NN + i) * NN + j)) * NOUT + o0;
        *(float4*)dst = v;
    }
}

// ---------------------------------------------------------------------------
extern "C" void kernel_launch(void* const* d_in, const int* in_sizes, int n_in,
                              void* d_out, int out_size, void* d_ws, size_t ws_size,
                              hipStream_t stream) {
    const float* x_l  = (const float*)d_in[0];
    const float* x_r  = (const float*)d_in[1];
    const float* Wl   = (const float*)d_in[2];
    const float* bl   = (const float*)d_in[3];
    const float* Wr   = (const float*)d_in[4];
    const float* br   = (const float*)d_in[5];
    const float* Wb   = (const float*)d_in[6];
    const float* bb   = (const float*)d_in[7];
    float* out = (float*)d_out;

    ushort* hl_bf = (ushort*)d_ws;                   // B*N*H = 131072
    ushort* hr_bf = hl_bf + BB * NN * HH;            // 131072
    ushort* Wt    = hr_bf + BB * NN * HH;            // 8*128*128 = 131072

    k1_kernel<<<272, 512, 0, stream>>>(x_l, x_r, Wl, bl, Wr, br, Wb,
                                       hl_bf, hr_bf, Wt);
    k2_kernel<<<dim3(NN / 128, NN / 16, BB), 512, 0, stream>>>(
        hl_bf, hr_bf, Wt, bb, out);
}